// Round 2
// baseline (1307.882 us; speedup 1.0000x reference)
//
#include <hip/hip_runtime.h>

typedef __bf16 bf16x8 __attribute__((ext_vector_type(8)));
typedef float  f32x4  __attribute__((ext_vector_type(4)));

struct alignas(8) U16x4 { unsigned short x, y, z, w; };

__device__ __forceinline__ unsigned short f2bf(float f) {
    union { float f; unsigned u; } v; v.f = f;
    unsigned u = v.u;
    return (unsigned short)((u + 0x7fffu + ((u >> 16) & 1u)) >> 16);  // RNE
}

// ---- prep: W1 [256x128] f32 -> W1t [128x256] bf16 ; W2 [128x128] -> W2t [128x128]
__global__ __launch_bounds__(256) void prep_weights(
    const float* __restrict__ W1, const float* __restrict__ W2,
    unsigned short* __restrict__ W1t, unsigned short* __restrict__ W2t)
{
    int tid = blockIdx.x * 256 + threadIdx.x;
    if (tid < 128 * 256) {
        int n = tid >> 8, k = tid & 255;
        W1t[tid] = f2bf(W1[k * 128 + n]);       // W1t[n][k] = W1[k][n]
    } else if (tid < 128 * 256 + 128 * 128) {
        int t = tid - 128 * 256;
        int n = t >> 7, k = t & 127;
        W2t[t] = f2bf(W2[k * 128 + n]);         // W2t[n][k] = W2[k][n]
    }
}

#define ETILE 64

__global__ __launch_bounds__(256) void edge_mlp(
    const float* __restrict__ x, const float* __restrict__ e, const float* __restrict__ u,
    const float* __restrict__ b1, const float* __restrict__ b2,
    const float* __restrict__ ln_g, const float* __restrict__ ln_b,
    const int* __restrict__ edge_index, const int* __restrict__ batch,
    const unsigned short* __restrict__ W1t, const unsigned short* __restrict__ W2t,
    float* __restrict__ out, int E)
{
    __shared__ __align__(16) unsigned short sA[ETILE * 256];   // 32KB attrs bf16, swizzled
    __shared__ __align__(16) unsigned short sH[4][16 * 128];   // 16KB h1 per-wave, swizzled
    __shared__ int sRow[ETILE], sCol[ETILE], sG[ETILE];

    const int tid  = threadIdx.x;
    const int e0   = blockIdx.x * ETILE;
    const int wave = tid >> 6;
    const int lane = tid & 63;
    const int lrow = lane & 15;          // A-row / B-col / C-col index
    const int lk   = (lane >> 4) * 8;    // k-offset within K=32 step

    if (tid < ETILE) {
        int eid = e0 + tid;
        int eidc = eid < E ? eid : (E - 1);
        int r = edge_index[eidc];            // sender
        int c = edge_index[E + eidc];        // receiver
        sRow[tid] = r; sCol[tid] = c; sG[tid] = batch[r];
    }
    __syncthreads();

    // ---- stage attrs tile: [edge][ 0:64)=e  [64:128)=x[col]  [128:192)=x[row]  [192:256)=u[g]
    #pragma unroll
    for (int i = 0; i < 16; ++i) {
        int idx  = i * 256 + tid;
        int seg  = idx >> 10;
        int rem  = idx & 1023;
        int edge = rem >> 4;
        int p    = rem & 15;                 // float4 index within the 64-float segment
        const float* src;
        if (seg == 0) {
            int ee = e0 + edge; if (ee >= E) ee = E - 1;
            src = e + (size_t)ee * 64 + p * 4;
        } else if (seg == 1) {
            src = x + (size_t)sCol[edge] * 64 + p * 4;
        } else if (seg == 2) {
            src = x + (size_t)sRow[edge] * 64 + p * 4;
        } else {
            src = u + (size_t)sG[edge] * 64 + p * 4;
        }
        float4 v = *(const float4*)src;
        U16x4 b; b.x = f2bf(v.x); b.y = f2bf(v.y); b.z = f2bf(v.z); b.w = f2bf(v.w);
        int bo = edge * 512 + seg * 128 + p * 8;
        bo ^= (edge & 7) << 4;               // bank-conflict swizzle
        *(U16x4*)((char*)sA + bo) = b;
    }
    __syncthreads();

    // ---- GEMM1: attrs[16x256] @ W1t -> h1[16x128] per wave
    f32x4 acc[8];
    #pragma unroll
    for (int n = 0; n < 8; ++n) acc[n] = (f32x4){0.f, 0.f, 0.f, 0.f};

    const int m_base = wave * 16;
    #pragma unroll
    for (int kk = 0; kk < 8; ++kk) {
        int m  = m_base + lrow;
        int bo = m * 512 + (kk * 32 + lk) * 2;
        bo ^= (m & 7) << 4;
        bf16x8 a = *(const bf16x8*)((const char*)sA + bo);
        #pragma unroll
        for (int n = 0; n < 8; ++n) {
            bf16x8 b = *(const bf16x8*)(W1t + (n * 16 + lrow) * 256 + kk * 32 + lk);
            acc[n] = __builtin_amdgcn_mfma_f32_16x16x32_bf16(a, b, acc[n], 0, 0, 0);
        }
    }

    // ---- bias1 + relu -> per-wave LDS (re-fragment for GEMM2 A operand)
    float bias1[8];
    #pragma unroll
    for (int n = 0; n < 8; ++n) bias1[n] = b1[n * 16 + lrow];

    unsigned short* hbuf = sH[wave];
    #pragma unroll
    for (int n = 0; n < 8; ++n) {
        #pragma unroll
        for (int r = 0; r < 4; ++r) {
            float v = acc[n][r] + bias1[n];
            v = v > 0.f ? v : 0.f;
            int row = (lane >> 4) * 4 + r;   // edge within wave's 16
            int col = n * 16 + lrow;         // hidden unit
            int bo  = row * 256 + col * 2;
            bo ^= (row & 7) << 4;
            *(unsigned short*)((char*)hbuf + bo) = f2bf(v);
        }
    }
    __syncthreads();

    // ---- GEMM2: h1[16x128] @ W2t -> h2[16x128]
    f32x4 acc2[8];
    #pragma unroll
    for (int n = 0; n < 8; ++n) acc2[n] = (f32x4){0.f, 0.f, 0.f, 0.f};

    #pragma unroll
    for (int kk = 0; kk < 4; ++kk) {
        int bo = lrow * 256 + (kk * 32 + lk) * 2;
        bo ^= (lrow & 7) << 4;
        bf16x8 a = *(const bf16x8*)((const char*)hbuf + bo);
        #pragma unroll
        for (int n = 0; n < 8; ++n) {
            bf16x8 b = *(const bf16x8*)(W2t + (n * 16 + lrow) * 128 + kk * 32 + lk);
            acc2[n] = __builtin_amdgcn_mfma_f32_16x16x32_bf16(a, b, acc2[n], 0, 0, 0);
        }
    }

    // ---- bias2 + relu + layernorm + store
    float bias2[8], g_[8], bb_[8];
    #pragma unroll
    for (int n = 0; n < 8; ++n) {
        bias2[n] = b2[n * 16 + lrow];
        g_[n]    = ln_g[n * 16 + lrow];
        bb_[n]   = ln_b[n * 16 + lrow];
    }

    float v[8][4];
    #pragma unroll
    for (int n = 0; n < 8; ++n)
        #pragma unroll
        for (int r = 0; r < 4; ++r) {
            float t = acc2[n][r] + bias2[n];
            v[n][r] = t > 0.f ? t : 0.f;
        }

    #pragma unroll
    for (int r = 0; r < 4; ++r) {
        float s = 0.f, s2 = 0.f;
        #pragma unroll
        for (int n = 0; n < 8; ++n) { s += v[n][r]; s2 += v[n][r] * v[n][r]; }
        #pragma unroll
        for (int m = 1; m < 16; m <<= 1) {   // reduce across the 16-lane group
            s  += __shfl_xor(s,  m, 64);
            s2 += __shfl_xor(s2, m, 64);
        }
        float mu   = s * (1.f / 128.f);
        float var  = s2 * (1.f / 128.f) - mu * mu;
        float rstd = rsqrtf(var + 1e-5f);

        int edge = e0 + m_base + (lane >> 4) * 4 + r;
        if (edge < E) {
            float* orow = out + (size_t)edge * 128;
            #pragma unroll
            for (int n = 0; n < 8; ++n)
                orow[n * 16 + lrow] = (v[n][r] - mu) * rstd * g_[n] + bb_[n];
        }
    }
}

extern "C" void kernel_launch(void* const* d_in, const int* in_sizes, int n_in,
                              void* d_out, int out_size, void* d_ws, size_t ws_size,
                              hipStream_t stream) {
    const float* x    = (const float*)d_in[0];
    const float* e    = (const float*)d_in[1];
    const float* u    = (const float*)d_in[2];
    const float* W1   = (const float*)d_in[3];
    const float* b1   = (const float*)d_in[4];
    const float* W2   = (const float*)d_in[5];
    const float* b2   = (const float*)d_in[6];
    const float* ln_g = (const float*)d_in[7];
    const float* ln_b = (const float*)d_in[8];
    const int*   edge_index = (const int*)d_in[9];
    const int*   batch      = (const int*)d_in[10];

    const int E = in_sizes[9] / 2;

    unsigned short* W1t = (unsigned short*)d_ws;          // 128*256 bf16
    unsigned short* W2t = W1t + 128 * 256;                // 128*128 bf16

    prep_weights<<<192, 256, 0, stream>>>(W1, W2, W1t, W2t);

    int nblk = (E + ETILE - 1) / ETILE;
    edge_mlp<<<nblk, 256, 0, stream>>>(x, e, u, b1, b2, ln_g, ln_b,
                                       edge_index, batch, W1t, W2t,
                                       (float*)d_out, E);
}

// Round 4
// 1077.076 us; speedup vs baseline: 1.2143x; 1.2143x over previous
//
#include <hip/hip_runtime.h>

typedef __bf16 bf16_t;
typedef __bf16 bf16x8 __attribute__((ext_vector_type(8)));
typedef float  f32x4  __attribute__((ext_vector_type(4)));
typedef unsigned short u16;

__device__ __forceinline__ u16 f2bf(float f) {
    union { float f; unsigned u; } v; v.f = f;
    unsigned u = v.u;
    return (u16)((u + 0x7fffu + ((u >> 16) & 1u)) >> 16);  // RNE
}

// ---- prep: W1 [256x128] f32 -> W1t [128x256] bf16 (transposed); W2 -> W2t [128x128]
__global__ __launch_bounds__(256) void prep_weights(
    const float* __restrict__ W1, const float* __restrict__ W2,
    u16* __restrict__ W1t, u16* __restrict__ W2t)
{
    int tid = blockIdx.x * 256 + threadIdx.x;
    if (tid < 128 * 256) {
        int n = tid >> 8, k = tid & 255;
        W1t[tid] = f2bf(W1[k * 128 + n]);
    } else if (tid < 128 * 256 + 128 * 128) {
        int t = tid - 128 * 256;
        int n = t >> 7, k = t & 127;
        W2t[t] = f2bf(W2[k * 128 + n]);
    }
}

// ---- prep: cast x, u to bf16
__global__ __launch_bounds__(256) void prep_cast(
    const float* __restrict__ x, const float* __restrict__ u,
    bf16_t* __restrict__ xb, bf16_t* __restrict__ ub, int nx, int nu)
{
    int total = (nx + nu) >> 2;
    for (int i = blockIdx.x * 256 + threadIdx.x; i < total; i += gridDim.x * 256) {
        int j = i << 2;
        const float* src; bf16_t* dst;
        if (j < nx) { src = x + j;        dst = xb + j; }
        else        { src = u + (j - nx); dst = ub + (j - nx); }
        float4 v = *(const float4*)src;
        dst[0] = (__bf16)v.x; dst[1] = (__bf16)v.y;
        dst[2] = (__bf16)v.z; dst[3] = (__bf16)v.w;
    }
}

__device__ __forceinline__ bf16x8 cvt8(const float* __restrict__ p) {
    float4 a = *(const float4*)p;
    float4 b = *(const float4*)(p + 4);
    bf16x8 r;
    r[0] = (__bf16)a.x; r[1] = (__bf16)a.y; r[2] = (__bf16)a.z; r[3] = (__bf16)a.w;
    r[4] = (__bf16)b.x; r[5] = (__bf16)b.y; r[6] = (__bf16)b.z; r[7] = (__bf16)b.w;
    return r;
}

// 32 edges per wave, 4 independent waves per block, zero block barriers.
template<bool PRECAST>
__global__ __launch_bounds__(256, 4) void edge_mlp(
    const float* __restrict__ x, const float* __restrict__ e, const float* __restrict__ u,
    const bf16_t* __restrict__ xb, const bf16_t* __restrict__ ub,
    const float* __restrict__ b1, const float* __restrict__ b2,
    const float* __restrict__ ln_g, const float* __restrict__ ln_b,
    const int* __restrict__ edge_index, const int* __restrict__ batch,
    const bf16_t* __restrict__ W1t, const bf16_t* __restrict__ W2t,
    float* __restrict__ out, int E)
{
    __shared__ __align__(16) u16 sH[4][32 * 128];   // 8KB per wave, swizzled

    const int wave = threadIdx.x >> 6;
    const int lane = threadIdx.x & 63;
    const int lrow = lane & 15;          // fragment row/col index
    const int kg   = lane >> 4;          // k-group
    const int lk   = kg * 8;             // k-octet offset

    const long tb = (long)(blockIdx.x * 4 + wave) * 32;
    if (tb >= E) return;

    const int eid0 = (int)tb + lrow;
    const int eid1 = eid0 + 16;
    const int r0 = edge_index[eid0],     r1 = edge_index[eid1];
    const int c0 = edge_index[E + eid0], c1 = edge_index[E + eid1];
    const int g0 = batch[r0],            g1 = batch[r1];

    const float*  ep0 = e + (size_t)eid0 * 64;
    const float*  ep1 = e + (size_t)eid1 * 64;

    // ---- GEMM1: attrs[32x256] @ W1t^T -> h1[32x128]
    f32x4 acc[2][8] = {};

    const bf16_t* w1b = W1t + lrow * 256 + lk;

    #pragma unroll
    for (int kk = 0; kk < 8; ++kk) {
        const int off = (kk & 1) * 32 + lk;
        bf16x8 a0, a1;
        if (kk < 2) {                       // seg 0: edge features (f32)
            a0 = cvt8(ep0 + off);
            a1 = cvt8(ep1 + off);
        } else if (kk < 4) {                // seg 1: receiver x[col]
            if (PRECAST) {
                a0 = *(const bf16x8*)(xb + (size_t)c0 * 64 + off);
                a1 = *(const bf16x8*)(xb + (size_t)c1 * 64 + off);
            } else {
                a0 = cvt8(x + (size_t)c0 * 64 + off);
                a1 = cvt8(x + (size_t)c1 * 64 + off);
            }
        } else if (kk < 6) {                // seg 2: sender x[row]
            if (PRECAST) {
                a0 = *(const bf16x8*)(xb + (size_t)r0 * 64 + off);
                a1 = *(const bf16x8*)(xb + (size_t)r1 * 64 + off);
            } else {
                a0 = cvt8(x + (size_t)r0 * 64 + off);
                a1 = cvt8(x + (size_t)r1 * 64 + off);
            }
        } else {                            // seg 3: globals u[batch[row]]
            if (PRECAST) {
                a0 = *(const bf16x8*)(ub + (size_t)g0 * 64 + off);
                a1 = *(const bf16x8*)(ub + (size_t)g1 * 64 + off);
            } else {
                a0 = cvt8(u + (size_t)g0 * 64 + off);
                a1 = cvt8(u + (size_t)g1 * 64 + off);
            }
        }
        #pragma unroll
        for (int n = 0; n < 8; ++n) {
            bf16x8 b = *(const bf16x8*)(w1b + n * 16 * 256 + kk * 32);
            acc[0][n] = __builtin_amdgcn_mfma_f32_16x16x32_bf16(a0, b, acc[0][n], 0, 0, 0);
            acc[1][n] = __builtin_amdgcn_mfma_f32_16x16x32_bf16(a1, b, acc[1][n], 0, 0, 0);
        }
    }

    // ---- bias1 + relu -> per-wave LDS (re-fragment for GEMM2 A)
    float bias1[8];
    #pragma unroll
    for (int n = 0; n < 8; ++n) bias1[n] = b1[n * 16 + lrow];

    u16* hb = sH[wave];
    #pragma unroll
    for (int m = 0; m < 2; ++m)
        #pragma unroll
        for (int n = 0; n < 8; ++n)
            #pragma unroll
            for (int r = 0; r < 4; ++r) {
                float v = acc[m][n][r] + bias1[n];
                v = v > 0.f ? v : 0.f;
                int row = m * 16 + kg * 4 + r;
                int bo  = row * 256 + (n * 16 + lrow) * 2;
                bo ^= (row & 7) << 4;       // bank-conflict swizzle
                *(u16*)((char*)hb + bo) = __builtin_bit_cast(u16, (__bf16)v);
            }

    asm volatile("s_waitcnt lgkmcnt(0)" ::: "memory");   // wave-local LDS write->read order
    __builtin_amdgcn_sched_barrier(0);

    // ---- GEMM2: h1[32x128] @ W2t^T -> h2[32x128]
    f32x4 acc2[2][8] = {};
    const bf16_t* w2b = W2t + lrow * 128 + lk;

    #pragma unroll
    for (int kk = 0; kk < 4; ++kk) {
        bf16x8 a0, a1;
        {
            int row = lrow;
            int bo  = row * 256 + (kk * 32 + lk) * 2;
            bo ^= (row & 7) << 4;
            a0 = *(const bf16x8*)((const char*)hb + bo);
        }
        {
            int row = 16 + lrow;
            int bo  = row * 256 + (kk * 32 + lk) * 2;
            bo ^= (row & 7) << 4;
            a1 = *(const bf16x8*)((const char*)hb + bo);
        }
        #pragma unroll
        for (int n = 0; n < 8; ++n) {
            bf16x8 b = *(const bf16x8*)(w2b + n * 16 * 128 + kk * 32);
            acc2[0][n] = __builtin_amdgcn_mfma_f32_16x16x32_bf16(a0, b, acc2[0][n], 0, 0, 0);
            acc2[1][n] = __builtin_amdgcn_mfma_f32_16x16x32_bf16(a1, b, acc2[1][n], 0, 0, 0);
        }
    }

    // ---- bias2 + relu (in place) + layernorm + store
    float bias2[8], gg[8], bb[8];
    #pragma unroll
    for (int n = 0; n < 8; ++n) {
        bias2[n] = b2[n * 16 + lrow];
        gg[n]    = ln_g[n * 16 + lrow];
        bb[n]    = ln_b[n * 16 + lrow];
    }

    #pragma unroll
    for (int m = 0; m < 2; ++m)
        #pragma unroll
        for (int n = 0; n < 8; ++n)
            #pragma unroll
            for (int r = 0; r < 4; ++r) {
                float t = acc2[m][n][r] + bias2[n];
                acc2[m][n][r] = t > 0.f ? t : 0.f;
            }

    #pragma unroll
    for (int m = 0; m < 2; ++m)
        #pragma unroll
        for (int r = 0; r < 4; ++r) {
            float s = 0.f, s2 = 0.f;
            #pragma unroll
            for (int n = 0; n < 8; ++n) {
                float v = acc2[m][n][r];
                s += v; s2 += v * v;
            }
            #pragma unroll
            for (int msk = 1; msk < 16; msk <<= 1) {
                s  += __shfl_xor(s,  msk, 64);
                s2 += __shfl_xor(s2, msk, 64);
            }
            float mu   = s * (1.f / 128.f);
            float var  = s2 * (1.f / 128.f) - mu * mu;
            float rstd = rsqrtf(var + 1e-5f);

            long edge = tb + m * 16 + kg * 4 + r;
            float* orow = out + (size_t)edge * 128;
            #pragma unroll
            for (int n = 0; n < 8; ++n)
                orow[n * 16 + lrow] = (acc2[m][n][r] - mu) * rstd * gg[n] + bb[n];
        }
}

extern "C" void kernel_launch(void* const* d_in, const int* in_sizes, int n_in,
                              void* d_out, int out_size, void* d_ws, size_t ws_size,
                              hipStream_t stream) {
    const float* x    = (const float*)d_in[0];
    const float* e    = (const float*)d_in[1];
    const float* u    = (const float*)d_in[2];
    const float* W1   = (const float*)d_in[3];
    const float* b1   = (const float*)d_in[4];
    const float* W2   = (const float*)d_in[5];
    const float* b2   = (const float*)d_in[6];
    const float* ln_g = (const float*)d_in[7];
    const float* ln_b = (const float*)d_in[8];
    const int*   edge_index = (const int*)d_in[9];
    const int*   batch      = (const int*)d_in[10];

    const int E  = in_sizes[9] / 2;
    const int nx = in_sizes[0];
    const int nu = in_sizes[2];

    u16* W1t = (u16*)d_ws;                       // 128*256 bf16 = 64KB
    u16* W2t = W1t + 128 * 256;                  // 128*128 bf16 = 32KB
    bf16_t* xbp = (bf16_t*)(W2t + 128 * 128);    // nx bf16
    bf16_t* ubp = xbp + nx;                      // nu bf16

    size_t needed = 98304 + (size_t)(nx + nu) * 2;
    bool precast = ws_size >= needed;

    prep_weights<<<192, 256, 0, stream>>>(W1, W2, W1t, W2t);

    int nblk = (E + 127) / 128;                  // 4 waves x 32 edges per block
    if (precast) {
        int cgrid = ((nx + nu) / 4 + 255) / 256;
        if (cgrid > 2048) cgrid = 2048;
        prep_cast<<<cgrid, 256, 0, stream>>>(x, u, xbp, ubp, nx, nu);
        edge_mlp<true><<<nblk, 256, 0, stream>>>(x, e, u, xbp, ubp, b1, b2, ln_g, ln_b,
                                                 edge_index, batch,
                                                 (const bf16_t*)W1t, (const bf16_t*)W2t,
                                                 (float*)d_out, E);
    } else {
        edge_mlp<false><<<nblk, 256, 0, stream>>>(x, e, u, nullptr, nullptr, b1, b2, ln_g, ln_b,
                                                  edge_index, batch,
                                                  (const bf16_t*)W1t, (const bf16_t*)W2t,
                                                  (float*)d_out, E);
    }
}